// Round 1
// baseline (1161.884 us; speedup 1.0000x reference)
//
#include <hip/hip_runtime.h>

typedef unsigned short u16;
typedef __attribute__((ext_vector_type(8))) short bf16x8;
typedef __attribute__((ext_vector_type(4))) float f32x4;

#define MFMA16(a, b, c) __builtin_amdgcn_mfma_f32_16x16x32_bf16((a), (b), (c), 0, 0, 0)

__device__ __forceinline__ u16 f2bf(float f) {
  unsigned u = __builtin_bit_cast(unsigned, f);
  u += 0x7FFFu + ((u >> 16) & 1u);   // round-to-nearest-even
  return (u16)(u >> 16);
}

// Swizzled LDS element indices (16-byte-block XOR swizzle to break row-stride bank conflicts).
// [64][256] bf16, row = 512 B = 32 blocks
__device__ __forceinline__ int idx256(int r, int c) {
  int blk = ((r << 5) + (c >> 3)) ^ (r & 7);
  return (blk << 3) + (c & 7);
}
// [64][32] bf16, row = 64 B = 4 blocks
__device__ __forceinline__ int idx32(int r, int c) {
  int blk = ((r << 2) + (c >> 3)) ^ (r & 3);
  return (blk << 3) + (c & 7);
}
// [.][64] bf16, row = 128 B = 8 blocks
__device__ __forceinline__ int idx64(int r, int c) {
  int blk = ((r << 3) + (c >> 3)) ^ (r & 7);
  return (blk << 3) + (c & 7);
}

// ---------------- kernel 0a: GroupNorm stats: mean + rstd per (b, g) ----------------
__global__ __launch_bounds__(256) void k_stats(const float* __restrict__ x,
                                               float* __restrict__ stats) {
  int b = blockIdx.x >> 5, g = blockIdx.x & 31;
  const float4* p = (const float4*)(x + ((size_t)((b << 8) + (g << 3)) << 16));
  float s = 0.f, ss = 0.f;
  for (int i = threadIdx.x; i < (8 * 65536) / 4; i += 256) {
    float4 v = p[i];
    s += v.x + v.y + v.z + v.w;
    ss += v.x * v.x + v.y * v.y + v.z * v.z + v.w * v.w;
  }
  #pragma unroll
  for (int off = 1; off < 64; off <<= 1) {
    s += __shfl_xor(s, off);
    ss += __shfl_xor(ss, off);
  }
  __shared__ float ls[4], lss[4];
  int wv = threadIdx.x >> 6;
  if ((threadIdx.x & 63) == 0) { ls[wv] = s; lss[wv] = ss; }
  __syncthreads();
  if (threadIdx.x == 0) {
    float S = ls[0] + ls[1] + ls[2] + ls[3];
    float SS = lss[0] + lss[1] + lss[2] + lss[3];
    const float inv = 1.f / 524288.f;
    float mean = S * inv;
    float var = SS * inv - mean * mean;
    stats[blockIdx.x * 2] = mean;
    stats[blockIdx.x * 2 + 1] = rsqrtf(var + 1e-5f);
  }
}

// ---------------- kernel 0b: weight bf16 conversion + bias table ----------------
__global__ __launch_bounds__(256) void k_prep(const float* __restrict__ qkv_w,
                                              const float* __restrict__ proj_w,
                                              const float* __restrict__ rpb,
                                              u16* __restrict__ qkvw,
                                              u16* __restrict__ projw,
                                              float* __restrict__ biast) {
  int i = blockIdx.x * 256 + threadIdx.x;
  if (i < 196608) qkvw[i] = f2bf(qkv_w[i]);
  if (i < 65536) projw[i] = f2bf(proj_w[i]);
  if (i < 32768) {
    int h = i >> 12, n = (i >> 6) & 63, m = i & 63;
    int nd = n >> 4, nh = (n >> 2) & 3, nw = n & 3;
    int md = m >> 4, mh = (m >> 2) & 3, mw = m & 3;
    int r = (nd - md + 3) * 49 + (nh - mh + 3) * 7 + (nw - mw + 3);
    biast[i] = rpb[r * 8 + h];
  }
}

// ---------------- main fused kernel: one block per window ----------------
__global__ __launch_bounds__(256) void k_main(
    const float* __restrict__ x, const float* __restrict__ norm_w,
    const float* __restrict__ norm_b, const float* __restrict__ qkv_b,
    const float* __restrict__ proj_b, const float* __restrict__ stats,
    const u16* __restrict__ qkvw, const u16* __restrict__ projw,
    const float* __restrict__ biast, float* __restrict__ out) {
  __shared__ __attribute__((aligned(16))) u16 sXN[16384];   // [64 tok][256 ch]
  __shared__ __attribute__((aligned(16))) u16 sATT[16384];  // [64 tok][256 ch]
  __shared__ __attribute__((aligned(16))) u16 sQ[8192];     // 4 waves x [64][32]
  __shared__ __attribute__((aligned(16))) u16 sK[8192];
  __shared__ __attribute__((aligned(16))) u16 sVT[8192];    // 4 waves x [32][64] (transposed V)
  __shared__ __attribute__((aligned(16))) u16 sP[16384];    // 4 waves x [64][64]
  __shared__ int toff[64];

  const int tid = threadIdx.x;
  const int wid = blockIdx.x;
  const int b = wid >> 10;
  const int wd = (wid >> 8) & 3, wh = (wid >> 4) & 15, ww = wid & 15;

  if (tid < 64) {
    int td = tid >> 4, th = (tid >> 2) & 3, tw = tid & 3;
    int sd = ((wd << 2) + td + 2) & 15;
    int sh = ((wh << 2) + th + 2) & 63;
    int sw = ((ww << 2) + tw + 2) & 63;
    toff[tid] = (sd << 12) + (sh << 6) + sw;  // spatial offset; gather pos == final scatter pos
  }
  __syncthreads();

  // -------- phase 1: gather + GroupNorm -> sXN (bf16) --------
  {
    const int c = tid;
    const int g = c >> 3;
    const float mean = stats[(((b << 5) + g) << 1)];
    const float rstd = stats[(((b << 5) + g) << 1) + 1];
    const float gw = norm_w[c] * rstd;
    const float gb = norm_b[c] - mean * gw;
    const float* xc = x + ((size_t)((b << 8) + c) << 16);
    #pragma unroll 8
    for (int t = 0; t < 64; ++t) {
      sXN[idx256(t, c)] = f2bf(fmaf(xc[toff[t]], gw, gb));
    }
  }
  __syncthreads();

  const int lane = tid & 63;
  const int wv = tid >> 6;
  const int lr = lane & 15;
  const int lg = lane >> 4;
  u16* qb = sQ + (wv << 11);
  u16* kb = sK + (wv << 11);
  u16* vb = sVT + (wv << 11);
  u16* pb = sP + (wv << 12);

  const float SCALE = 0.17677669529663687f;  // 32^-0.5

  for (int hi = 0; hi < 2; ++hi) {
    const int h = (wv << 1) + hi;
    // -------- QKV GEMMs for head h: out 64x32, K=256 --------
    for (int m3 = 0; m3 < 3; ++m3) {
      const int woff = m3 * 256 + (h << 5);
      f32x4 acc[4][2];
      #pragma unroll
      for (int tn = 0; tn < 2; ++tn) {
        float bv = qkv_b[woff + (tn << 4) + lr];
        f32x4 z = {bv, bv, bv, bv};
        #pragma unroll
        for (int tm = 0; tm < 4; ++tm) acc[tm][tn] = z;
      }
      #pragma unroll 2
      for (int kk = 0; kk < 8; ++kk) {
        const int c0 = kk << 5;
        bf16x8 a[4], bw[2];
        #pragma unroll
        for (int tm = 0; tm < 4; ++tm)
          a[tm] = *(const bf16x8*)&sXN[idx256((tm << 4) + lr, c0 + (lg << 3))];
        #pragma unroll
        for (int tn = 0; tn < 2; ++tn)
          bw[tn] = *(const bf16x8*)&qkvw[((woff + (tn << 4) + lr) << 8) + c0 + (lg << 3)];
        #pragma unroll
        for (int tm = 0; tm < 4; ++tm)
          #pragma unroll
          for (int tn = 0; tn < 2; ++tn)
            acc[tm][tn] = MFMA16(a[tm], bw[tn], acc[tm][tn]);
      }
      const float mult = (m3 == 0) ? SCALE : 1.0f;
      #pragma unroll
      for (int tm = 0; tm < 4; ++tm)
        #pragma unroll
        for (int tn = 0; tn < 2; ++tn)
          #pragma unroll
          for (int rj = 0; rj < 4; ++rj) {
            int row = (tm << 4) + (lg << 2) + rj;  // token
            int col = (tn << 4) + lr;              // head dim
            u16 v = f2bf(acc[tm][tn][rj] * mult);
            if (m3 == 0) qb[idx32(row, col)] = v;
            else if (m3 == 1) kb[idx32(row, col)] = v;
            else vb[idx64(col, row)] = v;          // store V transposed [d][m]
          }
    }
    __syncthreads();

    // -------- S = q k^T + bias (64x64, K=32) --------
    f32x4 s[4][4];
    #pragma unroll
    for (int tm = 0; tm < 4; ++tm)
      #pragma unroll
      for (int tn = 0; tn < 4; ++tn)
        #pragma unroll
        for (int rj = 0; rj < 4; ++rj)
          s[tm][tn][rj] =
              biast[(h << 12) + ((((tm << 4) + (lg << 2) + rj)) << 6) + (tn << 4) + lr];
    {
      bf16x8 aq[4], bk[4];
      #pragma unroll
      for (int tm = 0; tm < 4; ++tm)
        aq[tm] = *(const bf16x8*)&qb[idx32((tm << 4) + lr, lg << 3)];
      #pragma unroll
      for (int tn = 0; tn < 4; ++tn)
        bk[tn] = *(const bf16x8*)&kb[idx32((tn << 4) + lr, lg << 3)];
      #pragma unroll
      for (int tm = 0; tm < 4; ++tm)
        #pragma unroll
        for (int tn = 0; tn < 4; ++tn)
          s[tm][tn] = MFMA16(aq[tm], bk[tn], s[tm][tn]);
    }
    // -------- softmax over rows (16-lane groups hold a row across cols) --------
    #pragma unroll
    for (int tm = 0; tm < 4; ++tm)
      #pragma unroll
      for (int rj = 0; rj < 4; ++rj) {
        float mx = fmaxf(fmaxf(s[tm][0][rj], s[tm][1][rj]),
                         fmaxf(s[tm][2][rj], s[tm][3][rj]));
        #pragma unroll
        for (int off = 1; off < 16; off <<= 1) mx = fmaxf(mx, __shfl_xor(mx, off));
        float e0 = __expf(s[tm][0][rj] - mx);
        float e1 = __expf(s[tm][1][rj] - mx);
        float e2 = __expf(s[tm][2][rj] - mx);
        float e3 = __expf(s[tm][3][rj] - mx);
        float sum = e0 + e1 + e2 + e3;
        #pragma unroll
        for (int off = 1; off < 16; off <<= 1) sum += __shfl_xor(sum, off);
        float inv = 1.0f / sum;
        int row = (tm << 4) + (lg << 2) + rj;
        pb[idx64(row, lr)] = f2bf(e0 * inv);
        pb[idx64(row, 16 + lr)] = f2bf(e1 * inv);
        pb[idx64(row, 32 + lr)] = f2bf(e2 * inv);
        pb[idx64(row, 48 + lr)] = f2bf(e3 * inv);
      }
    __syncthreads();

    // -------- O = P V (64x32, K=64) --------
    f32x4 o[4][2];
    {
      f32x4 z = {0.f, 0.f, 0.f, 0.f};
      #pragma unroll
      for (int tm = 0; tm < 4; ++tm)
        #pragma unroll
        for (int tn = 0; tn < 2; ++tn) o[tm][tn] = z;
    }
    #pragma unroll
    for (int kk = 0; kk < 2; ++kk) {
      bf16x8 ap[4], bv2[2];
      #pragma unroll
      for (int tm = 0; tm < 4; ++tm)
        ap[tm] = *(const bf16x8*)&pb[idx64((tm << 4) + lr, (kk << 5) + (lg << 3))];
      #pragma unroll
      for (int tn = 0; tn < 2; ++tn)
        bv2[tn] = *(const bf16x8*)&vb[idx64((tn << 4) + lr, (kk << 5) + (lg << 3))];
      #pragma unroll
      for (int tm = 0; tm < 4; ++tm)
        #pragma unroll
        for (int tn = 0; tn < 2; ++tn)
          o[tm][tn] = MFMA16(ap[tm], bv2[tn], o[tm][tn]);
    }
    #pragma unroll
    for (int tm = 0; tm < 4; ++tm)
      #pragma unroll
      for (int tn = 0; tn < 2; ++tn)
        #pragma unroll
        for (int rj = 0; rj < 4; ++rj)
          sATT[idx256((tm << 4) + (lg << 2) + rj, (h << 5) + (tn << 4) + lr)] =
              f2bf(o[tm][tn][rj]);
    __syncthreads();
  }

  // -------- proj: out 64x256, K=256; wave wv owns cols [wv*64, wv*64+64) --------
  f32x4 pr[4][4];
  #pragma unroll
  for (int tn = 0; tn < 4; ++tn) {
    float bv = proj_b[(wv << 6) + (tn << 4) + lr];
    f32x4 z = {bv, bv, bv, bv};
    #pragma unroll
    for (int tm = 0; tm < 4; ++tm) pr[tm][tn] = z;
  }
  #pragma unroll 2
  for (int kk = 0; kk < 8; ++kk) {
    const int c0 = kk << 5;
    bf16x8 a[4], bw[4];
    #pragma unroll
    for (int tm = 0; tm < 4; ++tm)
      a[tm] = *(const bf16x8*)&sATT[idx256((tm << 4) + lr, c0 + (lg << 3))];
    #pragma unroll
    for (int tn = 0; tn < 4; ++tn)
      bw[tn] = *(const bf16x8*)&projw[(((wv << 6) + (tn << 4) + lr) << 8) + c0 + (lg << 3)];
    #pragma unroll
    for (int tm = 0; tm < 4; ++tm)
      #pragma unroll
      for (int tn = 0; tn < 4; ++tn)
        pr[tm][tn] = MFMA16(a[tm], bw[tn], pr[tm][tn]);
  }

  // -------- epilogue: residual add, scatter to (B,C,D,H,W) --------
  const float* xb = x + ((size_t)(b << 8) << 16);
  float* ob = out + ((size_t)(b << 8) << 16);
  #pragma unroll
  for (int tm = 0; tm < 4; ++tm)
    #pragma unroll
    for (int rj = 0; rj < 4; ++rj) {
      int n = (tm << 4) + (lg << 2) + rj;
      int off = toff[n];
      #pragma unroll
      for (int tn = 0; tn < 4; ++tn) {
        int oc = (wv << 6) + (tn << 4) + lr;
        size_t gi = ((size_t)oc << 16) + off;
        ob[gi] = xb[gi] + pr[tm][tn][rj];
      }
    }
}

extern "C" void kernel_launch(void* const* d_in, const int* in_sizes, int n_in,
                              void* d_out, int out_size, void* d_ws, size_t ws_size,
                              hipStream_t stream) {
  const float* x      = (const float*)d_in[0];
  const float* norm_w = (const float*)d_in[1];
  const float* norm_b = (const float*)d_in[2];
  const float* qkv_w  = (const float*)d_in[3];
  const float* qkv_b  = (const float*)d_in[4];
  const float* rpb    = (const float*)d_in[5];
  const float* proj_w = (const float*)d_in[6];
  const float* proj_b = (const float*)d_in[7];
  float* out = (float*)d_out;

  char* ws = (char*)d_ws;
  float* stats = (float*)ws;                            // 64*2*4   = 512 B
  u16* qkvw    = (u16*)(ws + 512);                      // 196608*2 = 393216 B
  u16* projw   = (u16*)(ws + 512 + 393216);             // 65536*2  = 131072 B
  float* biast = (float*)(ws + 512 + 393216 + 131072);  // 32768*4  = 131072 B

  hipLaunchKernelGGL(k_stats, dim3(64), dim3(256), 0, stream, x, stats);
  hipLaunchKernelGGL(k_prep, dim3(768), dim3(256), 0, stream, qkv_w, proj_w, rpb,
                     qkvw, projw, biast);
  hipLaunchKernelGGL(k_main, dim3(2048), dim3(256), 0, stream, x, norm_w, norm_b,
                     qkv_b, proj_b, stats, qkvw, projw, biast, out);
}

// Round 2
// 431.950 us; speedup vs baseline: 2.6899x; 2.6899x over previous
//
#include <hip/hip_runtime.h>

typedef unsigned short u16;
typedef __attribute__((ext_vector_type(4))) unsigned short u16x4;
typedef __attribute__((ext_vector_type(4))) unsigned int u32x4;
typedef __attribute__((ext_vector_type(8))) short bf16x8;
typedef __attribute__((ext_vector_type(4))) float f32x4;

#define MFMA16(a, b, c) __builtin_amdgcn_mfma_f32_16x16x32_bf16((a), (b), (c), 0, 0, 0)

__device__ __forceinline__ u16 f2bf(float f) {
  unsigned u = __builtin_bit_cast(unsigned, f);
  u += 0x7FFFu + ((u >> 16) & 1u);  // round-to-nearest-even
  return (u16)(u >> 16);
}
__device__ __forceinline__ float bf2f(u16 v) {
  return __builtin_bit_cast(float, (unsigned)v << 16);
}

// XOR-swizzled [64][256] bf16 for MFMA buffers: 16-B block (r*32 + c>>3)^(r&7)
__device__ __forceinline__ int idx256(int r, int c) {
  int blk = ((r << 5) + (c >> 3)) ^ (r & 7);
  return (blk << 3) + (c & 7);
}
// [64][32] bf16 per-wave q/k
__device__ __forceinline__ int idx32(int r, int c) {
  int blk = ((r << 2) + (c >> 3)) ^ (r & 3);
  return (blk << 3) + (c & 7);
}
// [.][64] bf16 per-wave P / V^T
__device__ __forceinline__ int idx64(int r, int c) {
  int blk = ((r << 3) + (c >> 3)) ^ (r & 7);
  return (blk << 3) + (c & 7);
}

// ---------------- stats pass 1: partial sums per (b,g,slice16) ----------------
__global__ __launch_bounds__(256) void k_stats1(const float* __restrict__ x,
                                                float* __restrict__ part) {
  int bid = blockIdx.x;            // (b*32+g)*16 + s
  int s = bid & 15, bg = bid >> 4;
  const float4* p = (const float4*)(x + ((size_t)bg << 19) + ((size_t)s << 15));
  float sm = 0.f, ss = 0.f;
  for (int i = threadIdx.x; i < 8192; i += 256) {
    float4 v = p[i];
    sm += v.x + v.y + v.z + v.w;
    ss += v.x * v.x + v.y * v.y + v.z * v.z + v.w * v.w;
  }
  #pragma unroll
  for (int off = 1; off < 64; off <<= 1) {
    sm += __shfl_xor(sm, off);
    ss += __shfl_xor(ss, off);
  }
  __shared__ float ls[4], lss[4];
  int wv = threadIdx.x >> 6;
  if ((threadIdx.x & 63) == 0) { ls[wv] = sm; lss[wv] = ss; }
  __syncthreads();
  if (threadIdx.x == 0) {
    part[bid * 2] = ls[0] + ls[1] + ls[2] + ls[3];
    part[bid * 2 + 1] = lss[0] + lss[1] + lss[2] + lss[3];
  }
}

// ---------------- stats pass 2: finalize mean/rstd ----------------
__global__ __launch_bounds__(64) void k_stats2(const float* __restrict__ part,
                                               float* __restrict__ stats) {
  int t = threadIdx.x;  // b*32+g
  float S = 0.f, SS = 0.f;
  #pragma unroll
  for (int s = 0; s < 16; ++s) {
    S += part[(t * 16 + s) * 2];
    SS += part[(t * 16 + s) * 2 + 1];
  }
  const float inv = 1.f / 524288.f;
  float mean = S * inv;
  float var = SS * inv - mean * mean;
  stats[t * 2] = mean;
  stats[t * 2 + 1] = rsqrtf(var + 1e-5f);
}

// ---------------- weight bf16 conversion + bias table ----------------
__global__ __launch_bounds__(256) void k_prep(const float* __restrict__ qkv_w,
                                              const float* __restrict__ proj_w,
                                              const float* __restrict__ rpb,
                                              u16* __restrict__ qkvw,
                                              u16* __restrict__ projw,
                                              float* __restrict__ biast) {
  int i = blockIdx.x * 256 + threadIdx.x;
  if (i < 196608) qkvw[i] = f2bf(qkv_w[i]);
  if (i < 65536) projw[i] = f2bf(proj_w[i]);
  if (i < 32768) {
    int h = i >> 12, n = (i >> 6) & 63, m = i & 63;
    int nd = n >> 4, nh = (n >> 2) & 3, nw = n & 3;
    int md = m >> 4, mh = (m >> 2) & 3, mw = m & 3;
    int r = (nd - md + 3) * 49 + (nh - mh + 3) * 7 + (nw - mw + 3);
    biast[i] = rpb[r * 8 + h];
  }
}

// ---------------- norm + window partition + transpose -> stage ----------------
// block = (b, sd, sh); reads x coalesced along W, writes stage rows contiguous.
__global__ __launch_bounds__(256) void k_win(const float* __restrict__ x,
                                             const float* __restrict__ norm_w,
                                             const float* __restrict__ norm_b,
                                             const float* __restrict__ stats,
                                             u16* __restrict__ stage) {
  __shared__ __attribute__((aligned(16))) u16 T[16384];  // [w][c], c rotated by w&252
  int bid = blockIdx.x;
  int b = bid >> 10, sd = (bid >> 6) & 15, sh = bid & 63;
  int wq = threadIdx.x & 15, c_lo = threadIdx.x >> 4;
  int w0 = wq << 2;

  for (int c_hi = 0; c_hi < 16; ++c_hi) {
    int c = (c_hi << 4) + c_lo;
    int g = c >> 3;
    float mean = stats[((b << 5) + g) * 2];
    float rstd = stats[((b << 5) + g) * 2 + 1];
    float gw = norm_w[c] * rstd;
    float gb = norm_b[c] - mean * gw;
    float4 v = *(const float4*)(x + (((size_t)(b * 256 + c)) << 16) + (sd << 12) +
                                (sh << 6) + w0);
    int cp = (c + w0) & 255;  // rotated column (same for j=0..3)
    T[((w0 + 0) << 8) + cp] = f2bf(fmaf(v.x, gw, gb));
    T[((w0 + 1) << 8) + cp] = f2bf(fmaf(v.y, gw, gb));
    T[((w0 + 2) << 8) + cp] = f2bf(fmaf(v.z, gw, gb));
    T[((w0 + 3) << 8) + cp] = f2bf(fmaf(v.w, gw, gb));
  }
  __syncthreads();

  int wv = threadIdx.x >> 6, l = threadIdx.x & 63;
  int ud = (sd + 14) & 15, wd = ud >> 2, td = ud & 3;
  int uh = (sh + 62) & 63, wh = uh >> 2, th = uh & 3;
  int winbase = (b << 10) + (wd << 8) + (wh << 4);
  int tokbase = (td << 4) + (th << 2);
  for (int it = 0; it < 16; ++it) {
    int sw = (it << 2) + wv;
    int uw = (sw + 62) & 63, ww = uw >> 2, tw = uw & 3;
    int row = ((winbase + ww) << 6) + tokbase + tw;
    u16x4 val = *(const u16x4*)&T[(sw << 8) + (((l << 2) + (sw & 252)) & 255)];
    *(u16x4*)&stage[((size_t)row << 8) + (l << 2)] = val;
  }
}

// ---------------- main fused attention: one block per window ----------------
__global__ __launch_bounds__(256) void k_main(
    const float* __restrict__ qkv_b, const float* __restrict__ proj_b,
    const u16* __restrict__ qkvw, const u16* __restrict__ projw,
    const float* __restrict__ biast, u16* __restrict__ stage) {
  __shared__ __attribute__((aligned(16))) u16 sXN[16384];   // [64 tok][256 ch] swz
  __shared__ __attribute__((aligned(16))) u16 sATT[16384];  // [64 tok][256 ch] swz
  __shared__ __attribute__((aligned(16))) u16 sQ[8192];
  __shared__ __attribute__((aligned(16))) u16 sK[8192];
  __shared__ __attribute__((aligned(16))) u16 sVT[8192];
  __shared__ __attribute__((aligned(16))) u16 sP[16384];

  const int tid = threadIdx.x;
  const int win = blockIdx.x;
  const int lane = tid & 63;
  const int wv = tid >> 6;
  const u16* wbase = stage + ((size_t)win << 14);

  // phase 1: coalesced 16-B block loads, pre-swizzled source -> linear LDS write
  // physical block p of row r holds source c-block (p ^ (r&7))  == idx256 layout
  #pragma unroll
  for (int it = 0; it < 8; ++it) {
    int r = (it << 3) + (wv << 1) + (lane >> 5);
    int p = lane & 31;
    u32x4 v = *(const u32x4*)(wbase + (r << 8) + ((p ^ (r & 7)) << 3));
    *(u32x4*)&sXN[(r << 8) + (p << 3)] = v;
  }
  __syncthreads();

  const int lr = lane & 15;
  const int lg = lane >> 4;
  u16* qb = sQ + (wv << 11);
  u16* kb = sK + (wv << 11);
  u16* vb = sVT + (wv << 11);
  u16* pb = sP + (wv << 12);

  const float SCALE = 0.17677669529663687f;  // 32^-0.5

  for (int hi = 0; hi < 2; ++hi) {
    const int h = (wv << 1) + hi;
    // QKV GEMMs for head h: 64x32, K=256
    for (int m3 = 0; m3 < 3; ++m3) {
      const int woff = m3 * 256 + (h << 5);
      f32x4 acc[4][2];
      #pragma unroll
      for (int tn = 0; tn < 2; ++tn) {
        float bv = qkv_b[woff + (tn << 4) + lr];
        f32x4 z = {bv, bv, bv, bv};
        #pragma unroll
        for (int tm = 0; tm < 4; ++tm) acc[tm][tn] = z;
      }
      #pragma unroll 2
      for (int kk = 0; kk < 8; ++kk) {
        const int c0 = kk << 5;
        bf16x8 a[4], bw[2];
        #pragma unroll
        for (int tm = 0; tm < 4; ++tm)
          a[tm] = *(const bf16x8*)&sXN[idx256((tm << 4) + lr, c0 + (lg << 3))];
        #pragma unroll
        for (int tn = 0; tn < 2; ++tn)
          bw[tn] = *(const bf16x8*)&qkvw[((woff + (tn << 4) + lr) << 8) + c0 + (lg << 3)];
        #pragma unroll
        for (int tm = 0; tm < 4; ++tm)
          #pragma unroll
          for (int tn = 0; tn < 2; ++tn)
            acc[tm][tn] = MFMA16(a[tm], bw[tn], acc[tm][tn]);
      }
      const float mult = (m3 == 0) ? SCALE : 1.0f;
      #pragma unroll
      for (int tm = 0; tm < 4; ++tm)
        #pragma unroll
        for (int tn = 0; tn < 2; ++tn)
          #pragma unroll
          for (int rj = 0; rj < 4; ++rj) {
            int row = (tm << 4) + (lg << 2) + rj;
            int col = (tn << 4) + lr;
            u16 v = f2bf(acc[tm][tn][rj] * mult);
            if (m3 == 0) qb[idx32(row, col)] = v;
            else if (m3 == 1) kb[idx32(row, col)] = v;
            else vb[idx64(col, row)] = v;
          }
    }

    // S = q k^T + bias (64x64, K=32)
    f32x4 s[4][4];
    #pragma unroll
    for (int tm = 0; tm < 4; ++tm)
      #pragma unroll
      for (int tn = 0; tn < 4; ++tn)
        #pragma unroll
        for (int rj = 0; rj < 4; ++rj)
          s[tm][tn][rj] =
              biast[(h << 12) + ((((tm << 4) + (lg << 2) + rj)) << 6) + (tn << 4) + lr];
    {
      bf16x8 aq[4], bk[4];
      #pragma unroll
      for (int tm = 0; tm < 4; ++tm)
        aq[tm] = *(const bf16x8*)&qb[idx32((tm << 4) + lr, lg << 3)];
      #pragma unroll
      for (int tn = 0; tn < 4; ++tn)
        bk[tn] = *(const bf16x8*)&kb[idx32((tn << 4) + lr, lg << 3)];
      #pragma unroll
      for (int tm = 0; tm < 4; ++tm)
        #pragma unroll
        for (int tn = 0; tn < 4; ++tn)
          s[tm][tn] = MFMA16(aq[tm], bk[tn], s[tm][tn]);
    }
    // softmax
    #pragma unroll
    for (int tm = 0; tm < 4; ++tm)
      #pragma unroll
      for (int rj = 0; rj < 4; ++rj) {
        float mx = fmaxf(fmaxf(s[tm][0][rj], s[tm][1][rj]),
                         fmaxf(s[tm][2][rj], s[tm][3][rj]));
        #pragma unroll
        for (int off = 1; off < 16; off <<= 1) mx = fmaxf(mx, __shfl_xor(mx, off));
        float e0 = __expf(s[tm][0][rj] - mx);
        float e1 = __expf(s[tm][1][rj] - mx);
        float e2 = __expf(s[tm][2][rj] - mx);
        float e3 = __expf(s[tm][3][rj] - mx);
        float sum = e0 + e1 + e2 + e3;
        #pragma unroll
        for (int off = 1; off < 16; off <<= 1) sum += __shfl_xor(sum, off);
        float inv = 1.0f / sum;
        int row = (tm << 4) + (lg << 2) + rj;
        pb[idx64(row, lr)] = f2bf(e0 * inv);
        pb[idx64(row, 16 + lr)] = f2bf(e1 * inv);
        pb[idx64(row, 32 + lr)] = f2bf(e2 * inv);
        pb[idx64(row, 48 + lr)] = f2bf(e3 * inv);
      }

    // O = P V (64x32, K=64)
    f32x4 o[4][2];
    {
      f32x4 z = {0.f, 0.f, 0.f, 0.f};
      #pragma unroll
      for (int tm = 0; tm < 4; ++tm)
        #pragma unroll
        for (int tn = 0; tn < 2; ++tn) o[tm][tn] = z;
    }
    #pragma unroll
    for (int kk = 0; kk < 2; ++kk) {
      bf16x8 ap[4], bv2[2];
      #pragma unroll
      for (int tm = 0; tm < 4; ++tm)
        ap[tm] = *(const bf16x8*)&pb[idx64((tm << 4) + lr, (kk << 5) + (lg << 3))];
      #pragma unroll
      for (int tn = 0; tn < 2; ++tn)
        bv2[tn] = *(const bf16x8*)&vb[idx64((tn << 4) + lr, (kk << 5) + (lg << 3))];
      #pragma unroll
      for (int tm = 0; tm < 4; ++tm)
        #pragma unroll
        for (int tn = 0; tn < 2; ++tn)
          o[tm][tn] = MFMA16(ap[tm], bv2[tn], o[tm][tn]);
    }
    #pragma unroll
    for (int tm = 0; tm < 4; ++tm)
      #pragma unroll
      for (int tn = 0; tn < 2; ++tn)
        #pragma unroll
        for (int rj = 0; rj < 4; ++rj)
          sATT[idx256((tm << 4) + (lg << 2) + rj, (h << 5) + (tn << 4) + lr)] =
              f2bf(o[tm][tn][rj]);
  }
  __syncthreads();  // sATT complete; also all waves done reading sXN

  // proj: 64x256, K=256; wave wv owns cols [wv*64, wv*64+64)
  f32x4 pr[4][4];
  #pragma unroll
  for (int tn = 0; tn < 4; ++tn) {
    float bv = proj_b[(wv << 6) + (tn << 4) + lr];
    f32x4 z = {bv, bv, bv, bv};
    #pragma unroll
    for (int tm = 0; tm < 4; ++tm) pr[tm][tn] = z;
  }
  #pragma unroll 2
  for (int kk = 0; kk < 8; ++kk) {
    const int c0 = kk << 5;
    bf16x8 a[4], bw[4];
    #pragma unroll
    for (int tm = 0; tm < 4; ++tm)
      a[tm] = *(const bf16x8*)&sATT[idx256((tm << 4) + lr, c0 + (lg << 3))];
    #pragma unroll
    for (int tn = 0; tn < 4; ++tn)
      bw[tn] = *(const bf16x8*)&projw[(((wv << 6) + (tn << 4) + lr) << 8) + c0 + (lg << 3)];
    #pragma unroll
    for (int tm = 0; tm < 4; ++tm)
      #pragma unroll
      for (int tn = 0; tn < 4; ++tn)
        pr[tm][tn] = MFMA16(a[tm], bw[tn], pr[tm][tn]);
  }

  // stage proj result through LDS (reuse sXN region, rotated-linear layout),
  // then write the window's stage rows back in-place, fully coalesced.
  #pragma unroll
  for (int tm = 0; tm < 4; ++tm)
    #pragma unroll
    for (int tn = 0; tn < 4; ++tn)
      #pragma unroll
      for (int rj = 0; rj < 4; ++rj) {
        int row = (tm << 4) + (lg << 2) + rj;
        int col = (wv << 6) + (tn << 4) + lr;
        sXN[(row << 8) + ((col + (row << 2)) & 255)] = f2bf(pr[tm][tn][rj]);
      }
  __syncthreads();
  u16* obase = stage + ((size_t)win << 14);
  #pragma unroll
  for (int it = 0; it < 16; ++it) {
    int r = (it << 2) + wv;
    u16x4 v = *(const u16x4*)&sXN[(r << 8) + (((lane << 2) + (r << 2)) & 255)];
    *(u16x4*)&obase[(r << 8) + (lane << 2)] = v;
  }
}

// ---------------- window reverse + residual ----------------
__global__ __launch_bounds__(256) void k_out(const float* __restrict__ x,
                                             const u16* __restrict__ stage,
                                             float* __restrict__ out) {
  __shared__ __attribute__((aligned(16))) u16 T[16384];
  int bid = blockIdx.x;
  int b = bid >> 10, sd = (bid >> 6) & 15, sh = bid & 63;
  int wv = threadIdx.x >> 6, l = threadIdx.x & 63;
  int ud = (sd + 14) & 15, wd = ud >> 2, td = ud & 3;
  int uh = (sh + 62) & 63, wh = uh >> 2, th = uh & 3;
  int winbase = (b << 10) + (wd << 8) + (wh << 4);
  int tokbase = (td << 4) + (th << 2);
  for (int it = 0; it < 16; ++it) {
    int sw = (it << 2) + wv;
    int uw = (sw + 62) & 63, ww = uw >> 2, tw = uw & 3;
    int row = ((winbase + ww) << 6) + tokbase + tw;
    u16x4 val = *(const u16x4*)&stage[((size_t)row << 8) + (l << 2)];
    *(u16x4*)&T[(sw << 8) + (((l << 2) + (sw & 252)) & 255)] = val;
  }
  __syncthreads();
  int wq = threadIdx.x & 15, c_lo = threadIdx.x >> 4;
  int w0 = wq << 2;
  for (int c_hi = 0; c_hi < 16; ++c_hi) {
    int c = (c_hi << 4) + c_lo;
    size_t gbase = (((size_t)(b * 256 + c)) << 16) + (sd << 12) + (sh << 6) + w0;
    float4 xv = *(const float4*)(x + gbase);
    int cp = (c + w0) & 255;
    float4 o;
    o.x = xv.x + bf2f(T[((w0 + 0) << 8) + cp]);
    o.y = xv.y + bf2f(T[((w0 + 1) << 8) + cp]);
    o.z = xv.z + bf2f(T[((w0 + 2) << 8) + cp]);
    o.w = xv.w + bf2f(T[((w0 + 3) << 8) + cp]);
    *(float4*)(out + gbase) = o;
  }
}

extern "C" void kernel_launch(void* const* d_in, const int* in_sizes, int n_in,
                              void* d_out, int out_size, void* d_ws, size_t ws_size,
                              hipStream_t stream) {
  const float* x      = (const float*)d_in[0];
  const float* norm_w = (const float*)d_in[1];
  const float* norm_b = (const float*)d_in[2];
  const float* qkv_w  = (const float*)d_in[3];
  const float* qkv_b  = (const float*)d_in[4];
  const float* rpb    = (const float*)d_in[5];
  const float* proj_w = (const float*)d_in[6];
  const float* proj_b = (const float*)d_in[7];
  float* out = (float*)d_out;

  char* ws = (char*)d_ws;
  float* stats = (float*)ws;                      // 512 B
  float* part  = (float*)(ws + 512);              // 8192 B
  u16* qkvw    = (u16*)(ws + 8704);               // 393216 B
  u16* projw   = (u16*)(ws + 401920);             // 131072 B
  float* biast = (float*)(ws + 532992);           // 131072 B
  u16* stage   = (u16*)(ws + 664064);             // 67108864 B (in-place in/out)

  hipLaunchKernelGGL(k_stats1, dim3(1024), dim3(256), 0, stream, x, part);
  hipLaunchKernelGGL(k_stats2, dim3(1), dim3(64), 0, stream, part, stats);
  hipLaunchKernelGGL(k_prep, dim3(768), dim3(256), 0, stream, qkv_w, proj_w, rpb,
                     qkvw, projw, biast);
  hipLaunchKernelGGL(k_win, dim3(2048), dim3(256), 0, stream, x, norm_w, norm_b,
                     stats, stage);
  hipLaunchKernelGGL(k_main, dim3(2048), dim3(256), 0, stream, qkv_b, proj_b,
                     qkvw, projw, biast, stage);
  hipLaunchKernelGGL(k_out, dim3(2048), dim3(256), 0, stream, x, stage, out);
}

// Round 4
// 431.844 us; speedup vs baseline: 2.6905x; 1.0002x over previous
//
#include <hip/hip_runtime.h>

typedef unsigned short u16;
typedef __attribute__((ext_vector_type(4))) unsigned short u16x4;
typedef __attribute__((ext_vector_type(4))) unsigned int u32x4;
typedef __attribute__((ext_vector_type(8))) short bf16x8;
typedef __attribute__((ext_vector_type(4))) float f32x4;

#define MFMA16(a, b, c) __builtin_amdgcn_mfma_f32_16x16x32_bf16((a), (b), (c), 0, 0, 0)

__device__ __forceinline__ u16 f2bf(float f) {
  unsigned u = __builtin_bit_cast(unsigned, f);
  u += 0x7FFFu + ((u >> 16) & 1u);  // round-to-nearest-even
  return (u16)(u >> 16);
}
__device__ __forceinline__ float bf2f(u16 v) {
  return __builtin_bit_cast(float, (unsigned)v << 16);
}

// XOR-swizzled [64][256] bf16: 16-B block (r*32 + c>>3)^(r&7)
__device__ __forceinline__ int idx256(int r, int c) {
  int blk = ((r << 5) + (c >> 3)) ^ (r & 7);
  return (blk << 3) + (c & 7);
}
// [64][32] staging for Q/K: key includes r>>2 so acc-scatter rows (lg*4+rj) spread
__device__ __forceinline__ int idxQ(int r, int c) {
  int blk = ((r << 2) + (c >> 3)) ^ ((r ^ (r >> 2)) & 3);
  return (blk << 3) + (c & 7);
}
// [32][64] staging for V^T / P-half
__device__ __forceinline__ int idx64(int r, int c) {
  int blk = ((r << 3) + (c >> 3)) ^ (r & 7);
  return (blk << 3) + (c & 7);
}

// ---------------- stats pass 1: partial sums per (b,g,slice16) ----------------
__global__ __launch_bounds__(256) void k_stats1(const float* __restrict__ x,
                                                float* __restrict__ part) {
  int bid = blockIdx.x;
  int s = bid & 15, bg = bid >> 4;
  const float4* p = (const float4*)(x + ((size_t)bg << 19) + ((size_t)s << 15));
  float sm = 0.f, ss = 0.f;
  for (int i = threadIdx.x; i < 8192; i += 256) {
    float4 v = p[i];
    sm += v.x + v.y + v.z + v.w;
    ss += v.x * v.x + v.y * v.y + v.z * v.z + v.w * v.w;
  }
  #pragma unroll
  for (int off = 1; off < 64; off <<= 1) {
    sm += __shfl_xor(sm, off);
    ss += __shfl_xor(ss, off);
  }
  __shared__ float ls[4], lss[4];
  int wv = threadIdx.x >> 6;
  if ((threadIdx.x & 63) == 0) { ls[wv] = sm; lss[wv] = ss; }
  __syncthreads();
  if (threadIdx.x == 0) {
    part[bid * 2] = ls[0] + ls[1] + ls[2] + ls[3];
    part[bid * 2 + 1] = lss[0] + lss[1] + lss[2] + lss[3];
  }
}

// ---------------- stats pass 2 ----------------
__global__ __launch_bounds__(64) void k_stats2(const float* __restrict__ part,
                                               float* __restrict__ stats) {
  int t = threadIdx.x;
  float S = 0.f, SS = 0.f;
  #pragma unroll
  for (int s = 0; s < 16; ++s) {
    S += part[(t * 16 + s) * 2];
    SS += part[(t * 16 + s) * 2 + 1];
  }
  const float inv = 1.f / 524288.f;
  float mean = S * inv;
  float var = SS * inv - mean * mean;
  stats[t * 2] = mean;
  stats[t * 2 + 1] = rsqrtf(var + 1e-5f);
}

// ---------------- weights bf16 + bias table [h][query][key] (round-2) ----------------
__global__ __launch_bounds__(256) void k_prep(const float* __restrict__ qkv_w,
                                              const float* __restrict__ proj_w,
                                              const float* __restrict__ rpb,
                                              u16* __restrict__ qkvw,
                                              u16* __restrict__ projw,
                                              float* __restrict__ biast) {
  int i = blockIdx.x * 256 + threadIdx.x;
  if (i < 196608) qkvw[i] = f2bf(qkv_w[i]);
  if (i < 65536) projw[i] = f2bf(proj_w[i]);
  if (i < 32768) {
    int h = i >> 12, n = (i >> 6) & 63, m = i & 63;
    int nd = n >> 4, nh = (n >> 2) & 3, nw = n & 3;
    int md = m >> 4, mh = (m >> 2) & 3, mw = m & 3;
    int r = (nd - md + 3) * 49 + (nh - mh + 3) * 7 + (nw - mw + 3);
    biast[i] = rpb[r * 8 + h];
  }
}

// ---------------- norm + window partition + transpose -> stage ----------------
__global__ __launch_bounds__(256) void k_win(const float* __restrict__ x,
                                             const float* __restrict__ norm_w,
                                             const float* __restrict__ norm_b,
                                             const float* __restrict__ stats,
                                             u16* __restrict__ stage) {
  __shared__ __attribute__((aligned(16))) u16 T[16384];
  int bid = blockIdx.x;
  int b = bid >> 10, sd = (bid >> 6) & 15, sh = bid & 63;
  int wq = threadIdx.x & 15, c_lo = threadIdx.x >> 4;
  int w0 = wq << 2;

  for (int c_hi = 0; c_hi < 16; ++c_hi) {
    int c = (c_hi << 4) + c_lo;
    int g = c >> 3;
    float mean = stats[((b << 5) + g) * 2];
    float rstd = stats[((b << 5) + g) * 2 + 1];
    float gw = norm_w[c] * rstd;
    float gb = norm_b[c] - mean * gw;
    float4 v = *(const float4*)(x + (((size_t)(b * 256 + c)) << 16) + (sd << 12) +
                                (sh << 6) + w0);
    int cp = (c + w0) & 255;
    T[((w0 + 0) << 8) + cp] = f2bf(fmaf(v.x, gw, gb));
    T[((w0 + 1) << 8) + cp] = f2bf(fmaf(v.y, gw, gb));
    T[((w0 + 2) << 8) + cp] = f2bf(fmaf(v.z, gw, gb));
    T[((w0 + 3) << 8) + cp] = f2bf(fmaf(v.w, gw, gb));
  }
  __syncthreads();

  int wv = threadIdx.x >> 6, l = threadIdx.x & 63;
  int ud = (sd + 14) & 15, wd = ud >> 2, td = ud & 3;
  int uh = (sh + 62) & 63, wh = uh >> 2, th = uh & 3;
  int winbase = (b << 10) + (wd << 8) + (wh << 4);
  int tokbase = (td << 4) + (th << 2);
  for (int it = 0; it < 16; ++it) {
    int sw = (it << 2) + wv;
    int uw = (sw + 62) & 63, ww = uw >> 2, tw = uw & 3;
    int row = ((winbase + ww) << 6) + tokbase + tw;
    u16x4 val = *(const u16x4*)&T[(sw << 8) + (((l << 2) + (sw & 252)) & 255)];
    *(u16x4*)&stage[((size_t)row << 8) + (l << 2)] = val;
  }
}

// ---------------- main fused attention: one block per window, 80 KB LDS ----------------
__global__ __launch_bounds__(256, 2) void k_main(
    const float* __restrict__ qkv_b, const float* __restrict__ proj_b,
    const u16* __restrict__ qkvw, const u16* __restrict__ projw,
    const float* __restrict__ biast, u16* __restrict__ stage) {
  __shared__ __attribute__((aligned(16))) u16 sXN[16384];   // 32 KB [64][256] swz
  __shared__ __attribute__((aligned(16))) u16 sATT[16384];  // 32 KB [64][256] swz
  __shared__ __attribute__((aligned(16))) u16 sW[8192];     // 16 KB: 4 KB per wave

  const int tid = threadIdx.x;
  const int win = blockIdx.x;
  const int lane = tid & 63;
  const int wv = tid >> 6;
  const int lr = lane & 15;
  const int lg = lane >> 4;
  const u16* wbase = stage + ((size_t)win << 14);

  // phase 1: coalesced pre-swizzled load of the window into sXN
  #pragma unroll
  for (int it = 0; it < 8; ++it) {
    int r = (it << 3) + (wv << 1) + (lane >> 5);
    int p = lane & 31;
    u32x4 v = *(const u32x4*)(wbase + (r << 8) + ((p ^ (r & 7)) << 3));
    *(u32x4*)&sXN[(r << 8) + (p << 3)] = v;
  }
  __syncthreads();

  u16* wb = sW + (wv << 11);  // per-wave 2048-elem (4 KB) scratch
  const float SCALE = 0.17677669529663687f;  // 32^-0.5

  #pragma unroll 1
  for (int hi = 0; hi < 2; ++hi) {
    const int h = (wv << 1) + hi;
    bf16x8 qf[4], kf[4], vf[2][2];

    // ---- QKV GEMMs (round-2 math), staged sequentially through wb ----
    #pragma unroll 1
    for (int m3 = 0; m3 < 3; ++m3) {
      const int woff = m3 * 256 + (h << 5);
      f32x4 acc[4][2];
      #pragma unroll
      for (int tn = 0; tn < 2; ++tn) {
        float bv = qkv_b[woff + (tn << 4) + lr];
        f32x4 z = {bv, bv, bv, bv};
        #pragma unroll
        for (int tm = 0; tm < 4; ++tm) acc[tm][tn] = z;
      }
      #pragma unroll 2
      for (int kk = 0; kk < 8; ++kk) {
        const int c0 = kk << 5;
        bf16x8 a[4], bw[2];
        #pragma unroll
        for (int tm = 0; tm < 4; ++tm)
          a[tm] = *(const bf16x8*)&sXN[idx256((tm << 4) + lr, c0 + (lg << 3))];
        #pragma unroll
        for (int tn = 0; tn < 2; ++tn)
          bw[tn] = *(const bf16x8*)&qkvw[((woff + (tn << 4) + lr) << 8) + c0 + (lg << 3)];
        #pragma unroll
        for (int tm = 0; tm < 4; ++tm)
          #pragma unroll
          for (int tn = 0; tn < 2; ++tn)
            acc[tm][tn] = MFMA16(a[tm], bw[tn], acc[tm][tn]);
      }
      if (m3 == 0) {
        // stage Q [64 tok][32 d], then read A-frags to registers
        #pragma unroll
        for (int tm = 0; tm < 4; ++tm)
          #pragma unroll
          for (int tn = 0; tn < 2; ++tn)
            #pragma unroll
            for (int rj = 0; rj < 4; ++rj)
              wb[idxQ((tm << 4) + (lg << 2) + rj, (tn << 4) + lr)] =
                  f2bf(acc[tm][tn][rj] * SCALE);
        #pragma unroll
        for (int t = 0; t < 4; ++t)
          qf[t] = *(const bf16x8*)&wb[idxQ((t << 4) + lr, lg << 3)];
      } else if (m3 == 1) {
        #pragma unroll
        for (int tm = 0; tm < 4; ++tm)
          #pragma unroll
          for (int tn = 0; tn < 2; ++tn)
            #pragma unroll
            for (int rj = 0; rj < 4; ++rj)
              wb[idxQ((tm << 4) + (lg << 2) + rj, (tn << 4) + lr)] =
                  f2bf(acc[tm][tn][rj]);
        #pragma unroll
        for (int t = 0; t < 4; ++t)
          kf[t] = *(const bf16x8*)&wb[idxQ((t << 4) + lr, lg << 3)];
      } else {
        // stage V^T [32 d][64 tok], then read B-frags
        #pragma unroll
        for (int tm = 0; tm < 4; ++tm)
          #pragma unroll
          for (int tn = 0; tn < 2; ++tn)
            #pragma unroll
            for (int rj = 0; rj < 4; ++rj)
              wb[idx64((tn << 4) + lr, (tm << 4) + (lg << 2) + rj)] =
                  f2bf(acc[tm][tn][rj]);
        #pragma unroll
        for (int tn = 0; tn < 2; ++tn)
          #pragma unroll
          for (int ks = 0; ks < 2; ++ks)
            vf[tn][ks] = *(const bf16x8*)&wb[idx64((tn << 4) + lr, (ks << 5) + (lg << 3))];
      }
    }

    // ---- S = Q K^T + bias (round-2 orientation: [query][key]) ----
    f32x4 s[4][4];
    #pragma unroll
    for (int tm = 0; tm < 4; ++tm)
      #pragma unroll
      for (int tn = 0; tn < 4; ++tn) {
        #pragma unroll
        for (int rj = 0; rj < 4; ++rj)
          s[tm][tn][rj] =
              biast[(h << 12) + ((((tm << 4) + (lg << 2) + rj)) << 6) + (tn << 4) + lr];
        s[tm][tn] = MFMA16(qf[tm], kf[tn], s[tm][tn]);
      }

    // ---- softmax over keys (round-2 exact) ----
    #pragma unroll
    for (int tm = 0; tm < 4; ++tm)
      #pragma unroll
      for (int rj = 0; rj < 4; ++rj) {
        float mx = fmaxf(fmaxf(s[tm][0][rj], s[tm][1][rj]),
                         fmaxf(s[tm][2][rj], s[tm][3][rj]));
        #pragma unroll
        for (int off = 1; off < 16; off <<= 1) mx = fmaxf(mx, __shfl_xor(mx, off));
        float e0 = __expf(s[tm][0][rj] - mx);
        float e1 = __expf(s[tm][1][rj] - mx);
        float e2 = __expf(s[tm][2][rj] - mx);
        float e3 = __expf(s[tm][3][rj] - mx);
        float sum = e0 + e1 + e2 + e3;
        #pragma unroll
        for (int off = 1; off < 16; off <<= 1) sum += __shfl_xor(sum, off);
        float inv = 1.0f / sum;
        s[tm][0][rj] = e0 * inv;
        s[tm][1][rj] = e1 * inv;
        s[tm][2][rj] = e2 * inv;
        s[tm][3][rj] = e3 * inv;
      }

    // ---- O = P V, P staged through wb in two 32-query halves ----
    #pragma unroll 1
    for (int half = 0; half < 2; ++half) {
      #pragma unroll
      for (int t2 = 0; t2 < 2; ++t2) {
        const int tm = (half << 1) + t2;
        #pragma unroll
        for (int tn = 0; tn < 4; ++tn)
          #pragma unroll
          for (int rj = 0; rj < 4; ++rj)
            wb[idx64((t2 << 4) + (lg << 2) + rj, (tn << 4) + lr)] =
                f2bf(s[tm][tn][rj]);
      }
      bf16x8 pf[2][2];
      #pragma unroll
      for (int t2 = 0; t2 < 2; ++t2)
        #pragma unroll
        for (int ks = 0; ks < 2; ++ks)
          pf[t2][ks] = *(const bf16x8*)&wb[idx64((t2 << 4) + lr, (ks << 5) + (lg << 3))];
      f32x4 o[2][2];
      {
        f32x4 z = {0.f, 0.f, 0.f, 0.f};
        #pragma unroll
        for (int t2 = 0; t2 < 2; ++t2)
          #pragma unroll
          for (int tn = 0; tn < 2; ++tn) o[t2][tn] = z;
      }
      #pragma unroll
      for (int ks = 0; ks < 2; ++ks)
        #pragma unroll
        for (int t2 = 0; t2 < 2; ++t2)
          #pragma unroll
          for (int tn = 0; tn < 2; ++tn)
            o[t2][tn] = MFMA16(pf[t2][ks], vf[tn][ks], o[t2][tn]);
      #pragma unroll
      for (int t2 = 0; t2 < 2; ++t2)
        #pragma unroll
        for (int tn = 0; tn < 2; ++tn)
          #pragma unroll
          for (int rj = 0; rj < 4; ++rj)
            sATT[idx256((half << 5) + (t2 << 4) + (lg << 2) + rj,
                        (h << 5) + (tn << 4) + lr)] = f2bf(o[t2][tn][rj]);
    }
  }
  __syncthreads();  // sATT complete; all sXN reads complete

  // ---- proj: 64x256, K=256; wave wv owns cols [wv*64, wv*64+64) ----
  f32x4 pr[4][4];
  #pragma unroll
  for (int tn = 0; tn < 4; ++tn) {
    float bv = proj_b[(wv << 6) + (tn << 4) + lr];
    f32x4 z = {bv, bv, bv, bv};
    #pragma unroll
    for (int tm = 0; tm < 4; ++tm) pr[tm][tn] = z;
  }
  #pragma unroll 2
  for (int kk = 0; kk < 8; ++kk) {
    const int c0 = kk << 5;
    bf16x8 a[4], bw[4];
    #pragma unroll
    for (int tm = 0; tm < 4; ++tm)
      a[tm] = *(const bf16x8*)&sATT[idx256((tm << 4) + lr, c0 + (lg << 3))];
    #pragma unroll
    for (int tn = 0; tn < 4; ++tn)
      bw[tn] = *(const bf16x8*)&projw[(((wv << 6) + (tn << 4) + lr) << 8) + c0 + (lg << 3)];
    #pragma unroll
    for (int tm = 0; tm < 4; ++tm)
      #pragma unroll
      for (int tn = 0; tn < 4; ++tn)
        pr[tm][tn] = MFMA16(a[tm], bw[tn], pr[tm][tn]);
  }

  // stage proj result through sXN (rotated-linear layout), write back coalesced
  #pragma unroll
  for (int tm = 0; tm < 4; ++tm)
    #pragma unroll
    for (int tn = 0; tn < 4; ++tn)
      #pragma unroll
      for (int rj = 0; rj < 4; ++rj) {
        int row = (tm << 4) + (lg << 2) + rj;
        int col = (wv << 6) + (tn << 4) + lr;
        sXN[(row << 8) + ((col + (row << 2)) & 255)] = f2bf(pr[tm][tn][rj]);
      }
  __syncthreads();
  u16* obase = stage + ((size_t)win << 14);
  #pragma unroll
  for (int it = 0; it < 16; ++it) {
    int r = (it << 2) + wv;
    u16x4 v = *(const u16x4*)&sXN[(r << 8) + (((lane << 2) + (r << 2)) & 255)];
    *(u16x4*)&obase[(r << 8) + (lane << 2)] = v;
  }
}

// ---------------- window reverse + residual ----------------
__global__ __launch_bounds__(256) void k_out(const float* __restrict__ x,
                                             const u16* __restrict__ stage,
                                             float* __restrict__ out) {
  __shared__ __attribute__((aligned(16))) u16 T[16384];
  int bid = blockIdx.x;
  int b = bid >> 10, sd = (bid >> 6) & 15, sh = bid & 63;
  int wv = threadIdx.x >> 6, l = threadIdx.x & 63;
  int ud = (sd + 14) & 15, wd = ud >> 2, td = ud & 3;
  int uh = (sh + 62) & 63, wh = uh >> 2, th = uh & 3;
  int winbase = (b << 10) + (wd << 8) + (wh << 4);
  int tokbase = (td << 4) + (th << 2);
  for (int it = 0; it < 16; ++it) {
    int sw = (it << 2) + wv;
    int uw = (sw + 62) & 63, ww = uw >> 2, tw = uw & 3;
    int row = ((winbase + ww) << 6) + tokbase + tw;
    u16x4 val = *(const u16x4*)&stage[((size_t)row << 8) + (l << 2)];
    *(u16x4*)&T[(sw << 8) + (((l << 2) + (sw & 252)) & 255)] = val;
  }
  __syncthreads();
  int wq = threadIdx.x & 15, c_lo = threadIdx.x >> 4;
  int w0 = wq << 2;
  for (int c_hi = 0; c_hi < 16; ++c_hi) {
    int c = (c_hi << 4) + c_lo;
    size_t gbase = (((size_t)(b * 256 + c)) << 16) + (sd << 12) + (sh << 6) + w0;
    float4 xv = *(const float4*)(x + gbase);
    int cp = (c + w0) & 255;
    float4 o;
    o.x = xv.x + bf2f(T[((w0 + 0) << 8) + cp]);
    o.y = xv.y + bf2f(T[((w0 + 1) << 8) + cp]);
    o.z = xv.z + bf2f(T[((w0 + 2) << 8) + cp]);
    o.w = xv.w + bf2f(T[((w0 + 3) << 8) + cp]);
    *(float4*)(out + gbase) = o;
  }
}

extern "C" void kernel_launch(void* const* d_in, const int* in_sizes, int n_in,
                              void* d_out, int out_size, void* d_ws, size_t ws_size,
                              hipStream_t stream) {
  const float* x      = (const float*)d_in[0];
  const float* norm_w = (const float*)d_in[1];
  const float* norm_b = (const float*)d_in[2];
  const float* qkv_w  = (const float*)d_in[3];
  const float* qkv_b  = (const float*)d_in[4];
  const float* rpb    = (const float*)d_in[5];
  const float* proj_w = (const float*)d_in[6];
  const float* proj_b = (const float*)d_in[7];
  float* out = (float*)d_out;

  char* ws = (char*)d_ws;
  float* stats = (float*)ws;                      // 512 B
  float* part  = (float*)(ws + 512);              // 8192 B
  u16* qkvw    = (u16*)(ws + 8704);               // 393216 B
  u16* projw   = (u16*)(ws + 401920);             // 131072 B
  float* biast = (float*)(ws + 532992);           // 131072 B
  u16* stage   = (u16*)(ws + 664064);             // 67108864 B

  hipLaunchKernelGGL(k_prep, dim3(768), dim3(256), 0, stream, qkv_w, proj_w, rpb,
                     qkvw, projw, biast);
  hipLaunchKernelGGL(k_stats1, dim3(1024), dim3(256), 0, stream, x, part);
  hipLaunchKernelGGL(k_stats2, dim3(1), dim3(64), 0, stream, part, stats);
  hipLaunchKernelGGL(k_win, dim3(2048), dim3(256), 0, stream, x, norm_w, norm_b,
                     stats, stage);
  hipLaunchKernelGGL(k_main, dim3(2048), dim3(256), 0, stream, qkv_b, proj_b,
                     qkvw, projw, biast, stage);
  hipLaunchKernelGGL(k_out, dim3(2048), dim3(256), 0, stream, x, stage, out);
}